// Round 9
// baseline (52.791 us; speedup 1.0000x reference)
//
#include <hip/hip_runtime.h>

#define DIM 1024
#define RPW 2        // rows per buffer (register tile = 2 rows)
#define WAVES 4      // waves per block
#define TPW 4        // tiles (row-pairs) per wave, software-pipelined 2-deep
#define NSTEP 24                            // stages 2..7 x 4 q
#define PACKED_BYTES (NSTEP * 64 * 8 * 4)   // 48 KB: wa region (24KB) + wb region (24KB)
#define WLDS_FLOATS (NSTEP * 64 * 8)        // 12288 floats

typedef float f32x4 __attribute__((ext_vector_type(4)));

// Butterfly mixer: 10 stages, stage i mixes (j, j+2^i) with Ws[i][p], p = j with bit i removed.
// Element j = q*256 + lane*4 + c lives in d[r][q*4+c]; bits{0,1}=c, {2..7}=lane, {8,9}=q.
// Stages 0,1,8,9 thread-local; stages 2..7 = __shfl_xor with mask 2^(i-2).
// r9: each wave streams TPW=4 row-pairs with a 2-deep register pipeline (named bufs,
// static indexing). 512 blocks -> 2 blocks/CU always resident; weight reads are
// loop-invariant (hoisted to regs / L1-hot). Stages 2..7 weights LDS-staged (r8).
// NOTE: never use the 2nd __launch_bounds__ arg (spill cliff: r2/r4).

__global__ void pack_weights(const float* __restrict__ Ws, float* __restrict__ pw) {
    int t = blockIdx.x * blockDim.x + threadIdx.x; // 0..1535
    if (t >= NSTEP * 64) return;
    int lane = t & 63;
    int step = t >> 6;            // 0..23
    int q = step & 3;
    int i = (step >> 2) + 2;      // 2..7
    int m = 1 << (i - 2);
    int a = (lane >> (i - 2)) & 1;
    int P0 = (((q * 64 + lane) >> (i - 1)) << i) | ((lane & (m - 1)) << 2);
    const float4* Wm = (const float4*)Ws;
    float4 wa, wb;
    float* pa = (float*)&wa;
    float* pb = (float*)&wb;
    #pragma unroll
    for (int e = 0; e < 4; ++e) {
        float4 M = Wm[i * 512 + P0 + e];
        pa[e] = a ? M.w : M.x;
        pb[e] = a ? M.y : M.z;
    }
    ((float4*)pw)[t] = wa;                       // wa region: [0, 6144) floats
    ((float4*)pw)[(WLDS_FLOATS / 8) + t] = wb;   // wb region: [6144, 12288) floats
}

__device__ __forceinline__ void load_pair(const float* __restrict__ x, int pair,
                                          int lane, float (&d)[RPW][16]) {
    const f32x4* src = (const f32x4*)(x + (size_t)pair * RPW * DIM);
    #pragma unroll
    for (int r = 0; r < RPW; ++r) {
        #pragma unroll
        for (int q = 0; q < 4; ++q) {
            f32x4 v = src[r * 256 + q * 64 + lane];   // plain load: L2-assisted
            d[r][q*4+0] = v.x; d[r][q*4+1] = v.y;
            d[r][q*4+2] = v.z; d[r][q*4+3] = v.w;
        }
    }
}

__device__ __forceinline__ void store_pair(float* __restrict__ out, int pair,
                                           int lane, float (&d)[RPW][16]) {
    f32x4* dst = (f32x4*)(out + (size_t)pair * RPW * DIM);
    #pragma unroll
    for (int r = 0; r < RPW; ++r) {
        #pragma unroll
        for (int q = 0; q < 4; ++q) {
            f32x4 v;
            v.x = d[r][q*4+0]; v.y = d[r][q*4+1];
            v.z = d[r][q*4+2]; v.w = d[r][q*4+3];
            __builtin_nontemporal_store(v, &dst[r * 256 + q * 64 + lane]);
        }
    }
}

template <bool PACKED>
__device__ __forceinline__ void compute_pair(float (&d)[RPW][16],
                                             const float4* __restrict__ Wm,
                                             const float* __restrict__ wsrc, // LDS (PACKED) base
                                             int lane) {
    // ---- stage 0: pairs (c,c+1); p = q*128 + lane*2 + (c>>1) ----
    #pragma unroll
    for (int q = 0; q < 4; ++q) {
        int base = 0*512 + q*128 + lane*2;
        float4 m0 = Wm[base], m1 = Wm[base+1];
        #pragma unroll
        for (int r = 0; r < RPW; ++r) {
            int e = q*4;
            float u = d[r][e+0], v = d[r][e+1];
            d[r][e+0] = u*m0.x + v*m0.z;
            d[r][e+1] = u*m0.y + v*m0.w;
            u = d[r][e+2]; v = d[r][e+3];
            d[r][e+2] = u*m1.x + v*m1.z;
            d[r][e+3] = u*m1.y + v*m1.w;
        }
    }

    // ---- stage 1: pairs (c,c+2); p = q*128 + lane*2 + (c&1) ----
    #pragma unroll
    for (int q = 0; q < 4; ++q) {
        int base = 1*512 + q*128 + lane*2;
        float4 m0 = Wm[base], m1 = Wm[base+1];
        #pragma unroll
        for (int r = 0; r < RPW; ++r) {
            int e = q*4;
            float u = d[r][e+0], v = d[r][e+2];
            d[r][e+0] = u*m0.x + v*m0.z;
            d[r][e+2] = u*m0.y + v*m0.w;
            u = d[r][e+1]; v = d[r][e+3];
            d[r][e+1] = u*m1.x + v*m1.z;
            d[r][e+3] = u*m1.y + v*m1.w;
        }
    }

    // ---- stages 2..7: cross-lane, mask m = 2^(i-2); weights from LDS (PACKED) ----
    #pragma unroll
    for (int i = 2; i < 8; ++i) {
        const int m = 1 << (i - 2);
        #pragma unroll
        for (int q = 0; q < 4; ++q) {
            const int step = (i - 2) * 4 + q;
            float wA0, wA1, wA2, wA3, wB0, wB1, wB2, wB3;
            if (PACKED) {
                f32x4 wa = *(const f32x4*)&wsrc[(step * 64 + lane) * 4];
                f32x4 wb = *(const f32x4*)&wsrc[(WLDS_FLOATS / 2) + (step * 64 + lane) * 4];
                wA0 = wa.x; wA1 = wa.y; wA2 = wa.z; wA3 = wa.w;
                wB0 = wb.x; wB1 = wb.y; wB2 = wb.z; wB3 = wb.w;
            } else {
                const int a = (lane >> (i - 2)) & 1;
                int P0 = (((q*64 + lane) >> (i-1)) << i) | ((lane & (m-1)) << 2);
                int base = i*512 + P0;
                float4 M0 = Wm[base+0], M1 = Wm[base+1], M2 = Wm[base+2], M3 = Wm[base+3];
                wA0 = a ? M0.w : M0.x; wB0 = a ? M0.y : M0.z;
                wA1 = a ? M1.w : M1.x; wB1 = a ? M1.y : M1.z;
                wA2 = a ? M2.w : M2.x; wB2 = a ? M2.y : M2.z;
                wA3 = a ? M3.w : M3.x; wB3 = a ? M3.y : M3.z;
            }
            #pragma unroll
            for (int r = 0; r < RPW; ++r) {
                int e = q*4;
                float o0 = __shfl_xor(d[r][e+0], m);
                float o1 = __shfl_xor(d[r][e+1], m);
                float o2 = __shfl_xor(d[r][e+2], m);
                float o3 = __shfl_xor(d[r][e+3], m);
                d[r][e+0] = d[r][e+0]*wA0 + o0*wB0;
                d[r][e+1] = d[r][e+1]*wA1 + o1*wB1;
                d[r][e+2] = d[r][e+2]*wA2 + o2*wB2;
                d[r][e+3] = d[r][e+3]*wA3 + o3*wB3;
            }
        }
    }

    // ---- stage 8: pairs (q, q+1) for q in {0,2}; p = (q>>1)*256 + lane*4 + c ----
    #pragma unroll
    for (int qp = 0; qp < 2; ++qp) {
        int base = 8*512 + qp*256 + lane*4;
        float4 M0 = Wm[base+0], M1 = Wm[base+1], M2 = Wm[base+2], M3 = Wm[base+3];
        #pragma unroll
        for (int r = 0; r < RPW; ++r) {
            int eu = (2*qp)*4, ev = (2*qp+1)*4;
            float u, v;
            u = d[r][eu+0]; v = d[r][ev+0]; d[r][eu+0] = u*M0.x + v*M0.z; d[r][ev+0] = u*M0.y + v*M0.w;
            u = d[r][eu+1]; v = d[r][ev+1]; d[r][eu+1] = u*M1.x + v*M1.z; d[r][ev+1] = u*M1.y + v*M1.w;
            u = d[r][eu+2]; v = d[r][ev+2]; d[r][eu+2] = u*M2.x + v*M2.z; d[r][ev+2] = u*M2.y + v*M2.w;
            u = d[r][eu+3]; v = d[r][ev+3]; d[r][eu+3] = u*M3.x + v*M3.z; d[r][ev+3] = u*M3.y + v*M3.w;
        }
    }

    // ---- stage 9: pairs (q, q+2) for q in {0,1}; p = (q&1)*256 + lane*4 + c ----
    #pragma unroll
    for (int qp = 0; qp < 2; ++qp) {
        int base = 9*512 + qp*256 + lane*4;
        float4 M0 = Wm[base+0], M1 = Wm[base+1], M2 = Wm[base+2], M3 = Wm[base+3];
        #pragma unroll
        for (int r = 0; r < RPW; ++r) {
            int eu = qp*4, ev = (qp+2)*4;
            float u, v;
            u = d[r][eu+0]; v = d[r][ev+0]; d[r][eu+0] = u*M0.x + v*M0.z; d[r][ev+0] = u*M0.y + v*M0.w;
            u = d[r][eu+1]; v = d[r][ev+1]; d[r][eu+1] = u*M1.x + v*M1.z; d[r][ev+1] = u*M1.y + v*M1.w;
            u = d[r][eu+2]; v = d[r][ev+2]; d[r][eu+2] = u*M2.x + v*M2.z; d[r][ev+2] = u*M2.y + v*M2.w;
            u = d[r][eu+3]; v = d[r][ev+3]; d[r][eu+3] = u*M3.x + v*M3.z; d[r][ev+3] = u*M3.y + v*M3.w;
        }
    }
}

template <bool PACKED>
__global__ __launch_bounds__(256) void butterfly_kernel(
    const float* __restrict__ x,
    const float* __restrict__ Ws,
    const float* __restrict__ pw,
    float* __restrict__ out,
    int npairs)
{
    const int lane = threadIdx.x & 63;
    const int wave = threadIdx.x >> 6;
    const int g = blockIdx.x * WAVES + wave;     // global wave id
    const int p0 = g * TPW;                      // first row-pair of this wave

    const float4* __restrict__ Wm = (const float4*)Ws;

    __shared__ float wlds[WLDS_FLOATS];   // 48 KB -> <=3 blocks/CU

    // ---- stage packed weights into LDS: 48 chunks of 1KB, 12 per wave ----
    if (PACKED) {
        #pragma unroll
        for (int k = 0; k < 12; ++k) {
            int chunk = wave * 12 + k;                 // 0..47
            const float* gsrc = pw + chunk * 256 + lane * 4;
            float* l = &wlds[chunk * 256 + lane * 4];
            __builtin_amdgcn_global_load_lds(gsrc, l, 16, 0, 0);
        }
    }

    float dA[RPW][16], dB[RPW][16];

    const bool h0 = (p0 + 0) < npairs;
    const bool h1 = (p0 + 1) < npairs;
    const bool h2 = (p0 + 2) < npairs;
    const bool h3 = (p0 + 3) < npairs;

    if (h0) load_pair(x, p0 + 0, lane, dA);          // tile 0 loads in flight
    if (PACKED) __syncthreads();                      // LDS staging complete

    if (h1) load_pair(x, p0 + 1, lane, dB);          // prefetch t1
    if (h0) { compute_pair<PACKED>(dA, Wm, wlds, lane); store_pair(out, p0 + 0, lane, dA); }

    if (h2) load_pair(x, p0 + 2, lane, dA);          // prefetch t2
    if (h1) { compute_pair<PACKED>(dB, Wm, wlds, lane); store_pair(out, p0 + 1, lane, dB); }

    if (h3) load_pair(x, p0 + 3, lane, dB);          // prefetch t3
    if (h2) { compute_pair<PACKED>(dA, Wm, wlds, lane); store_pair(out, p0 + 2, lane, dA); }

    if (h3) { compute_pair<PACKED>(dB, Wm, wlds, lane); store_pair(out, p0 + 3, lane, dB); }
}

extern "C" void kernel_launch(void* const* d_in, const int* in_sizes, int n_in,
                              void* d_out, int out_size, void* d_ws, size_t ws_size,
                              hipStream_t stream) {
    const float* x  = (const float*)d_in[0];
    const float* Ws = (const float*)d_in[1];
    float* out = (float*)d_out;

    int rows = in_sizes[0] / DIM;
    int npairs = rows / RPW;                               // 8192
    int pairs_per_block = WAVES * TPW;                     // 16
    int grid = (npairs + pairs_per_block - 1) / pairs_per_block;   // 512

    if (ws_size >= (size_t)PACKED_BYTES) {
        float* pw = (float*)d_ws;
        pack_weights<<<6, 256, 0, stream>>>(Ws, pw);
        butterfly_kernel<true><<<grid, 256, 0, stream>>>(x, Ws, pw, out, npairs);
    } else {
        butterfly_kernel<false><<<grid, 256, 0, stream>>>(x, Ws, nullptr, out, npairs);
    }
}